// Round 4
// baseline (512.560 us; speedup 1.0000x reference)
//
#include <hip/hip_runtime.h>

// GRU cell, B=16384, E=H=1024. fp32 in/out, bf16 MFMA compute.
//
// R4 changes vs R3:
//  - __launch_bounds__(256,4): force <=128 regs/wave -> 4 blocks/CU (16 waves).
//    ZR grid 2048 = exactly 2 residency waves, H grid 1024 = exactly 1 (no tail).
//  - gemm_zr / gemm_h as distinct symbols so rocprof separates them.
//  - register diet: int LDS offsets instead of pointer arrays.
// Structure:
//   ZR: [x|h](16384x2048) @ Bzr^T(2048x2048) -> ztb=bf16(sigmoid), ab=bf16(h*sig)
//   H:  [x|ab](16384x2048) @ Wh^T(1024x2048) -> out = h + z*(tanh-h), fp32
// GEMM: 128x128 tile, BK=32, 4 waves (2x2), 4x4 f32x4 acc, mfma 16x16x32 bf16,
// global_load_lds width16, XCD swizzle (8 consecutive blocks share one A-tile).

typedef short bf16x8 __attribute__((ext_vector_type(8)));
typedef float f32x4 __attribute__((ext_vector_type(4)));

static __device__ __forceinline__ unsigned short f2bf(float f) {
    unsigned int u = __float_as_uint(f);
    return (unsigned short)((u + 0x7fffu + ((u >> 16) & 1u)) >> 16);
}
static __device__ __forceinline__ float bf2f(unsigned short s) {
    return __uint_as_float(((unsigned int)s) << 16);
}

// ---- cast x and h to bf16 in one launch ------------------------------------
__global__ void cast2_f32_bf16(const float* __restrict__ a,
                               const float* __restrict__ b,
                               unsigned short* __restrict__ da,
                               unsigned short* __restrict__ db, int n) {
    int i = (blockIdx.x * blockDim.x + threadIdx.x) * 4;
    const float* s;
    unsigned short* d;
    int off;
    if (i < n) { s = a; d = da; off = i; }
    else       { s = b; d = db; off = i - n; }
    float4 v = *(const float4*)(s + off);
    ushort4 o;
    o.x = f2bf(v.x); o.y = f2bf(v.y); o.z = f2bf(v.z); o.w = f2bf(v.w);
    *(ushort4*)(d + off) = o;
}

// ---- transpose+cast all 6 weights in one launch ----------------------------
struct TPlan {
    const float* src[6];
    unsigned short* dst[6];  // pre-offset; row stride 2048
};
__global__ void transpose_cast6(TPlan p) {
    __shared__ float t[32][33];
    const float* src = p.src[blockIdx.z];
    unsigned short* dst = p.dst[blockIdx.z];
    int bx = blockIdx.x, by = blockIdx.y;
    int tx = threadIdx.x, ty = threadIdx.y;  // 32 x 8
#pragma unroll
    for (int i = 0; i < 4; ++i)
        t[ty + 8 * i][tx] = src[(by * 32 + ty + 8 * i) * 1024 + bx * 32 + tx];
    __syncthreads();
#pragma unroll
    for (int i = 0; i < 4; ++i) {
        int n = bx * 32 + ty + 8 * i;  // dst row (N)
        int k = by * 32 + tx;          // dst col (K)
        dst[n * 2048 + k] = f2bf(t[tx][ty + 8 * i]);
    }
}

// ---- shared GEMM body -------------------------------------------------------
// MODE 0 (ZR): N=2048; cols<1024: ztb=bf16(sigmoid(v+bz)), else ab=bf16(h*sig(v+br))
// MODE 1 (H):  N=1024; out = h + z*(tanh(v+bz) - h)
template <int MODE, int NBN_LOG>
static __device__ __forceinline__ void gemm_body(
        const unsigned short* __restrict__ Alo,
        const unsigned short* __restrict__ Ahi,
        const unsigned short* __restrict__ Bt,
        const float* __restrict__ bias_z,
        const float* __restrict__ bias_r,
        const unsigned short* __restrict__ hb,
        const unsigned short* __restrict__ ztb_in,
        const float* __restrict__ hf,
        unsigned short* __restrict__ ztb_out,
        unsigned short* __restrict__ ab_out,
        float* __restrict__ out) {
    constexpr int NBN = 1 << NBN_LOG;
    __shared__ __attribute__((aligned(16))) short As[128 * 32];
    __shared__ __attribute__((aligned(16))) short Bs[128 * 32];

    const int t = threadIdx.x;
    const int lane = t & 63;
    const int wave = t >> 6;
    // XCD swizzle: 8 consecutive blockIdx (one per XCD? no-- stride-8 siblings)
    // share bm within an XCD: i%8 = bml -> same XCD sees bn=0..NBN-1 of one bm
    // consecutively -> A-tile (512 KB) stays in that XCD's L2.
    const int i = blockIdx.x;
    const int bml = i & 7;
    const int bn = (i >> 3) & (NBN - 1);
    const int bmg = i >> (3 + NBN_LOG);
    const int bm = bmg * 8 + bml;
    const int wm = wave >> 1, wn = wave & 1;

    f32x4 acc[4][4] = {};

    const int rowA0 = bm * 128;
    const int rowB0 = bn * 128;
    const int koff = (lane >> 4) * 8;
    const int rsub = lane & 15;

    // LDS fragment offsets (elements), loop-invariant
    const int aoff = (wm * 64 + rsub) * 32 + koff;  // + mi*512
    const int boff = (wn * 64 + rsub) * 32 + koff;  // + ni*512

    // staging offsets, loop-invariant per thread
    const int c0 = wave * 64 + lane;          // j=0 chunk id
    const int row0s = c0 >> 2, part0 = c0 & 3;
    const int c1 = 256 + wave * 64 + lane;    // j=1 chunk id
    const int row1s = c1 >> 2, part1 = c1 & 3;
    short* ldsA0 = As + c0 * 8;
    short* ldsA1 = As + c1 * 8;
    short* ldsB0 = Bs + c0 * 8;
    short* ldsB1 = Bs + c1 * 8;

    for (int half = 0; half < 2; ++half) {
        const unsigned short* Ab = (half ? Ahi : Alo) + rowA0 * 1024;
        const unsigned short* Bb = Bt + rowB0 * 2048 + half * 1024;
        for (int kk = 0; kk < 1024; kk += 32) {
            const unsigned short* Asrc = Ab + kk;
            const unsigned short* Bsrc = Bb + kk;

            __syncthreads();  // previous iteration's ds_reads complete
            __builtin_amdgcn_global_load_lds(
                (const __attribute__((address_space(1))) void*)(Asrc + row0s * 1024 + part0 * 8),
                (__attribute__((address_space(3))) void*)ldsA0, 16, 0, 0);
            __builtin_amdgcn_global_load_lds(
                (const __attribute__((address_space(1))) void*)(Bsrc + row0s * 2048 + part0 * 8),
                (__attribute__((address_space(3))) void*)ldsB0, 16, 0, 0);
            __builtin_amdgcn_global_load_lds(
                (const __attribute__((address_space(1))) void*)(Asrc + row1s * 1024 + part1 * 8),
                (__attribute__((address_space(3))) void*)ldsA1, 16, 0, 0);
            __builtin_amdgcn_global_load_lds(
                (const __attribute__((address_space(1))) void*)(Bsrc + row1s * 2048 + part1 * 8),
                (__attribute__((address_space(3))) void*)ldsB1, 16, 0, 0);
            __syncthreads();  // staging complete (implicit vmcnt(0))

            bf16x8 af[4], bfr[4];
#pragma unroll
            for (int mi = 0; mi < 4; ++mi)
                af[mi] = *(const bf16x8*)(As + aoff + mi * 512);
#pragma unroll
            for (int ni = 0; ni < 4; ++ni)
                bfr[ni] = *(const bf16x8*)(Bs + boff + ni * 512);
#pragma unroll
            for (int mi = 0; mi < 4; ++mi)
#pragma unroll
                for (int ni = 0; ni < 4; ++ni)
                    acc[mi][ni] = __builtin_amdgcn_mfma_f32_16x16x32_bf16(
                        af[mi], bfr[ni], acc[mi][ni], 0, 0, 0);
        }
    }

    // Epilogue. C/D layout: col = lane&15, row = (lane>>4)*4 + reg  [m89]
    const int q = lane >> 4;
#pragma unroll
    for (int mi = 0; mi < 4; ++mi) {
#pragma unroll
        for (int ni = 0; ni < 4; ++ni) {
            int colg = bn * 128 + wn * 64 + ni * 16 + rsub;
            int row0 = bm * 128 + wm * 64 + mi * 16 + q * 4;
            if (MODE == 0) {
                bool isZ = colg < 1024;  // block-uniform
                int col = colg & 1023;
                float bz = isZ ? bias_z[col] : bias_r[col];
#pragma unroll
                for (int r = 0; r < 4; ++r) {
                    int idx = (row0 + r) * 1024 + col;
                    float v = acc[mi][ni][r] + bz;
                    float s = 1.0f / (1.0f + __expf(-v));
                    if (isZ) ztb_out[idx] = f2bf(s);
                    else     ab_out[idx] = f2bf(bf2f(hb[idx]) * s);
                }
            } else {
                int col = colg;
                float bz = bias_z[col];
#pragma unroll
                for (int r = 0; r < 4; ++r) {
                    int idx = (row0 + r) * 1024 + col;
                    float v = acc[mi][ni][r] + bz;
                    float e = __expf(2.0f * v);          // tanh, saturation-safe
                    float ht = 1.0f - 2.0f / (e + 1.0f);
                    float hv = hf[idx];
                    float z = bf2f(ztb_in[idx]);
                    out[idx] = fmaf(z, ht - hv, hv);
                }
            }
        }
    }
}

__global__ __launch_bounds__(256, 4)
void gemm_zr(const unsigned short* __restrict__ Alo,
             const unsigned short* __restrict__ Ahi,
             const unsigned short* __restrict__ Bt,
             const float* __restrict__ bias_z,
             const float* __restrict__ bias_r,
             const unsigned short* __restrict__ hb,
             unsigned short* __restrict__ ztb_out,
             unsigned short* __restrict__ ab_out) {
    gemm_body<0, 4>(Alo, Ahi, Bt, bias_z, bias_r, hb,
                    nullptr, nullptr, ztb_out, ab_out, nullptr);
}

__global__ __launch_bounds__(256, 4)
void gemm_h(const unsigned short* __restrict__ Alo,
            const unsigned short* __restrict__ Ahi,
            const unsigned short* __restrict__ Bt,
            const float* __restrict__ bias_z,
            const unsigned short* __restrict__ ztb_in,
            const float* __restrict__ hf,
            float* __restrict__ out) {
    gemm_body<1, 3>(Alo, Ahi, Bt, bias_z, nullptr, nullptr,
                    ztb_in, hf, nullptr, nullptr, out);
}

extern "C" void kernel_launch(void* const* d_in, const int* in_sizes, int n_in,
                              void* d_out, int out_size, void* d_ws, size_t ws_size,
                              hipStream_t stream) {
    const float* x    = (const float*)d_in[0];
    const float* h    = (const float*)d_in[1];
    const float* W_ri = (const float*)d_in[2];
    const float* b_ri = (const float*)d_in[3];
    const float* W_rh = (const float*)d_in[4];
    const float* W_zi = (const float*)d_in[5];
    const float* b_zi = (const float*)d_in[6];
    const float* W_zh = (const float*)d_in[7];
    const float* W_hi = (const float*)d_in[8];
    const float* b_hi = (const float*)d_in[9];
    const float* W_hh = (const float*)d_in[10];
    float* out = (float*)d_out;

    const size_t MB = 1024ull * 1024ull;
    char* ws = (char*)d_ws;
    unsigned short* xb   = (unsigned short*)(ws);             // 32 MB
    unsigned short* hb   = (unsigned short*)(ws + 32 * MB);   // 32 MB
    unsigned short* ab   = (unsigned short*)(ws + 64 * MB);   // 32 MB
    unsigned short* ztb  = (unsigned short*)(ws + 96 * MB);   // 32 MB
    unsigned short* Bzr  = (unsigned short*)(ws + 128 * MB);  // 8 MB  [2048][2048]
    unsigned short* Bh   = (unsigned short*)(ws + 136 * MB);  // 4 MB  [1024][2048]

    const int NELEM = 16384 * 1024;
    cast2_f32_bf16<<<2 * NELEM / (256 * 4), 256, 0, stream>>>(x, h, xb, hb, NELEM);

    TPlan p;
    p.src[0] = W_zi; p.dst[0] = Bzr + 0 * 2048 + 0;
    p.src[1] = W_zh; p.dst[1] = Bzr + 0 * 2048 + 1024;
    p.src[2] = W_ri; p.dst[2] = Bzr + 1024 * 2048 + 0;
    p.src[3] = W_rh; p.dst[3] = Bzr + 1024 * 2048 + 1024;
    p.src[4] = W_hi; p.dst[4] = Bh + 0;
    p.src[5] = W_hh; p.dst[5] = Bh + 1024;
    transpose_cast6<<<dim3(32, 32, 6), dim3(32, 8), 0, stream>>>(p);

    // ZR: 128 bm * 16 bn = 2048 blocks (= 2 residency waves at 4/CU)
    // H:  128 bm * 8 bn  = 1024 blocks (= 1 residency wave, no tail)
    gemm_zr<<<2048, 256, 0, stream>>>(xb, hb, Bzr, b_zi, b_ri, hb, ztb, ab);
    gemm_h<<<1024, 256, 0, stream>>>(xb, ab, Bh, b_hi, ztb, h, out);
}